// Round 18
// baseline (834.610 us; speedup 1.0000x reference)
//
#include <hip/hip_runtime.h>
#include <hip/hip_bf16.h>
#include <stdint.h>

typedef __bf16 bf16x8 __attribute__((ext_vector_type(8)));
typedef float f32x4 __attribute__((ext_vector_type(4)));
typedef unsigned short u16x8 __attribute__((ext_vector_type(8)));

#define DEVINL static __device__ __forceinline__

// f32 -> bf16 round-to-nearest-even (finite values)
DEVINL unsigned short f2bf(float f) {
  unsigned u = __builtin_bit_cast(unsigned, f);
  unsigned r = (u + 0x7FFFu + ((u >> 16) & 1u)) >> 16;
  return (unsigned short)r;
}
DEVINL float bf2f(unsigned short u) {
  return __builtin_bit_cast(float, ((unsigned)u) << 16);
}

DEVINL void gload_lds16(const unsigned short* g, unsigned short* l) {
  __builtin_amdgcn_global_load_lds(
      (const __attribute__((address_space(1))) void*)g,
      (__attribute__((address_space(3))) void*)l, 16, 0, 0);
}

// ---- embed + qkv-weight cvt, one launch (heterogeneous grid) -------------
__global__ __launch_bounds__(256) void embed_cvtq_kernel(
    const int* __restrict__ x, const float* __restrict__ tok,
    const float* __restrict__ pos, unsigned short* __restrict__ hb,
    const float* __restrict__ wq, const float* __restrict__ wk,
    const float* __restrict__ wv, unsigned short* __restrict__ wqkvb)
{
  if (blockIdx.x >= 8192) {
    const int b = blockIdx.x - 8192;  // 0..511
    for (long i = (long)b * 256 + threadIdx.x; i < 786432; i += 512 * 256) {
      const float* src;
      long off;
      if (i < 262144)      { src = wq; off = i; }
      else if (i < 524288) { src = wk; off = i - 262144; }
      else                 { src = wv; off = i - 524288; }
      float4 v = ((const float4*)src)[off];
      ushort4 o;
      o.x = f2bf(v.x); o.y = f2bf(v.y); o.z = f2bf(v.z); o.w = f2bf(v.w);
      ((ushort4*)wqkvb)[i] = o;
    }
    return;
  }
  const int bs = blockIdx.x;           // 0..8191  (b*2048 + s)
  const int s  = bs & 2047;
  const long trow = (long)x[bs] * 1024;
  const int d = threadIdx.x * 4;
  const float4 t = *(const float4*)(tok + trow + d);
  const float4 p = *(const float4*)(pos + (long)s * 1024 + d);
  ushort4 o;
  o.x = f2bf(t.x + p.x);
  o.y = f2bf(t.y + p.y);
  o.z = f2bf(t.z + p.z);
  o.w = f2bf(t.w + p.w);
  *(ushort4*)(hb + (long)bs * 1024 + d) = o;
}

// ---------------- GEMM: C[m,n] = scale * sum_k A[m,k]*B[n,k] + bias[n] ----
// m97-structure 128x128 kernel — used for PV.
template<int OUTMODE>
__global__ __launch_bounds__(256) void gemm_bt(
    const unsigned short* __restrict__ A, const unsigned short* __restrict__ B,
    void* __restrict__ Cout, const float* __restrict__ bias,
    float scale, int M, int N, int K,
    long sA, long sB, long sC, int Mb, long tStride, int mapMode)
{
  __shared__ __align__(16) unsigned short lA[128 * 32];
  __shared__ __align__(16) unsigned short lB[128 * 32];
  const int tid = threadIdx.x, wid = tid >> 6, lane = tid & 63;
  int bx, by, bz;
  if (mapMode == 0) {
    bx = blockIdx.x; by = blockIdx.y; bz = blockIdx.z;
  } else {
    const int bid = blockIdx.x;
    const int g = bid & 7, jj = bid >> 3;
    bz = g >> 1;
    by = (g & 1) * 8 + (jj & 7);
    bx = jj >> 3;
  }
  A += (long)bz * sA;
  B += (long)bz * sB;
  const int bm = by * 128, bn = bx * 128;

  const int c0 = wid * 64 + lane, c1 = c0 + 256;
  const unsigned short* gA0 = A + (long)(bm + (c0 >> 2)) * K + (c0 & 3) * 8;
  const unsigned short* gA1 = A + (long)(bm + (c1 >> 2)) * K + (c1 & 3) * 8;
  const unsigned short* gB0 = B + (long)(bn + (c0 >> 2)) * K + (c0 & 3) * 8;
  const unsigned short* gB1 = B + (long)(bn + (c1 >> 2)) * K + (c1 & 3) * 8;
  unsigned short* lA0 = lA + wid * 512;
  unsigned short* lA1 = lA + 2048 + wid * 512;
  unsigned short* lB0 = lB + wid * 512;
  unsigned short* lB1 = lB + 2048 + wid * 512;

  const int wr = (wid >> 1) * 64, wc = (wid & 1) * 64;
  const int lr = lane & 15, lk = (lane >> 4) * 8;

  f32x4 acc[4][4] = {};
  const int nk = K >> 5;
  for (int kt = 0; kt < nk; ++kt) {
    const int ko = kt << 5;
    gload_lds16(gA0 + ko, lA0);
    gload_lds16(gA1 + ko, lA1);
    gload_lds16(gB0 + ko, lB0);
    gload_lds16(gB1 + ko, lB1);
    __syncthreads();
    bf16x8 af[4], bg[4];
#pragma unroll
    for (int m = 0; m < 4; ++m)
      af[m] = *(const bf16x8*)(const void*)(lA + (wr + m * 16 + lr) * 32 + lk);
#pragma unroll
    for (int n = 0; n < 4; ++n)
      bg[n] = *(const bf16x8*)(const void*)(lB + (wc + n * 16 + lr) * 32 + lk);
#pragma unroll
    for (int m = 0; m < 4; ++m)
#pragma unroll
      for (int n = 0; n < 4; ++n)
        acc[m][n] = __builtin_amdgcn_mfma_f32_16x16x32_bf16(af[m], bg[n],
                                                            acc[m][n], 0, 0, 0);
    __syncthreads();
  }

  const int r0 = bm + wr + ((lane >> 4) << 2);
  const int cbase = bn + wc + lr;
#pragma unroll
  for (int n = 0; n < 4; ++n) {
    const int col = cbase + n * 16;
    const float bv = bias ? bias[col] : 0.f;
#pragma unroll
    for (int m = 0; m < 4; ++m) {
      const int row0 = r0 + m * 16;
      if (OUTMODE == 2) {
        float* C = (float*)Cout + (long)bz * sC;
#pragma unroll
        for (int i = 0; i < 4; ++i)
          C[(long)(row0 + i) * N + col] = acc[m][n][i] * scale + bv;
      } else if (OUTMODE == 0) {
        unsigned short* C = (unsigned short*)Cout + (long)bz * sC;
#pragma unroll
        for (int i = 0; i < 4; ++i)
          C[(long)(row0 + i) * N + col] = f2bf(acc[m][n][i] * scale + bv);
      } else {  // transposed write Vt[b][col][srow]
        unsigned short* C = (unsigned short*)Cout;
        const int b = row0 / Mb;
        const int srow = row0 - b * Mb;
        ushort4 o;
        o.x = f2bf(acc[m][n][0] * scale + bv);
        o.y = f2bf(acc[m][n][1] * scale + bv);
        o.z = f2bf(acc[m][n][2] * scale + bv);
        o.w = f2bf(acc[m][n][3] * scale + bv);
        *(ushort4*)(C + (long)b * tStride + (long)col * Mb + srow) = o;
      }
    }
  }
}

// ---- scores GEMM + Wfc cvt, one launch (heterogeneous grid) --------------
__global__ __launch_bounds__(256) void scores_cvt_kernel(
    const unsigned short* __restrict__ Qb, const unsigned short* __restrict__ Kb,
    unsigned short* __restrict__ Sc,
    const float* __restrict__ wfc, unsigned short* __restrict__ wfcb)
{
  __shared__ __align__(16) unsigned short lA[128 * 32];
  __shared__ __align__(16) unsigned short lB[128 * 32];
  if (blockIdx.x < 1024) {
    for (long i = (long)blockIdx.x * 256 + threadIdx.x; i < 8192000;
         i += 1024 * 256) {
      float4 v = ((const float4*)wfc)[i];
      ushort4 o;
      o.x = f2bf(v.x); o.y = f2bf(v.y); o.z = f2bf(v.z); o.w = f2bf(v.w);
      ((ushort4*)wfcb)[i] = o;
    }
    return;
  }
  constexpr int K = 1024, N = 2048;
  const int tid = threadIdx.x, wid = tid >> 6, lane = tid & 63;
  const int bid = blockIdx.x - 1024;            // 0..1023
  const int g = bid & 7, jj = bid >> 3;
  const int bz = g >> 1;
  const int by = (g & 1) * 8 + (jj & 7);
  const int bx = jj >> 3;
  const unsigned short* A = Qb + (long)bz * (2048L * 1024);
  const unsigned short* B = Kb + (long)bz * (2048L * 1024);
  unsigned short* C = Sc + (long)bz * (2048L * 2048);
  const int bm = by * 128, bn = bx * 128;

  const int c0 = wid * 64 + lane, c1 = c0 + 256;
  const unsigned short* gA0 = A + (long)(bm + (c0 >> 2)) * K + (c0 & 3) * 8;
  const unsigned short* gA1 = A + (long)(bm + (c1 >> 2)) * K + (c1 & 3) * 8;
  const unsigned short* gB0 = B + (long)(bn + (c0 >> 2)) * K + (c0 & 3) * 8;
  const unsigned short* gB1 = B + (long)(bn + (c1 >> 2)) * K + (c1 & 3) * 8;
  unsigned short* lA0 = lA + wid * 512;
  unsigned short* lA1 = lA + 2048 + wid * 512;
  unsigned short* lB0 = lB + wid * 512;
  unsigned short* lB1 = lB + 2048 + wid * 512;

  const int wr = (wid >> 1) * 64, wc = (wid & 1) * 64;
  const int lr = lane & 15, lk = (lane >> 4) * 8;

  f32x4 acc[4][4] = {};
  for (int kt = 0; kt < 32; ++kt) {
    const int ko = kt << 5;
    gload_lds16(gA0 + ko, lA0);
    gload_lds16(gA1 + ko, lA1);
    gload_lds16(gB0 + ko, lB0);
    gload_lds16(gB1 + ko, lB1);
    __syncthreads();
    bf16x8 af[4], bg[4];
#pragma unroll
    for (int m = 0; m < 4; ++m)
      af[m] = *(const bf16x8*)(const void*)(lA + (wr + m * 16 + lr) * 32 + lk);
#pragma unroll
    for (int n = 0; n < 4; ++n)
      bg[n] = *(const bf16x8*)(const void*)(lB + (wc + n * 16 + lr) * 32 + lk);
#pragma unroll
    for (int m = 0; m < 4; ++m)
#pragma unroll
      for (int n = 0; n < 4; ++n)
        acc[m][n] = __builtin_amdgcn_mfma_f32_16x16x32_bf16(af[m], bg[n],
                                                            acc[m][n], 0, 0, 0);
    __syncthreads();
  }

  const int r0 = bm + wr + ((lane >> 4) << 2);
  const int cbase = bn + wc + lr;
#pragma unroll
  for (int n = 0; n < 4; ++n) {
    const int col = cbase + n * 16;
#pragma unroll
    for (int m = 0; m < 4; ++m) {
      const int row0 = r0 + m * 16;
#pragma unroll
      for (int i = 0; i < 4; ++i)
        C[(long)(row0 + i) * N + col] = f2bf(acc[m][n][i] * 0.03125f);
    }
  }
}

// ---------------- row softmax in place over 2048 bf16 ---------------------
__global__ __launch_bounds__(256) void softmax_kernel(unsigned short* __restrict__ S)
{
  unsigned short* row = S + (long)blockIdx.x * 2048;
  const int t = threadIdx.x, lane = t & 63, wid = t >> 6;
  __shared__ float redm[4], reds[4];
  u16x8 raw = ((const u16x8*)row)[t];
  float v[8];
#pragma unroll
  for (int j = 0; j < 8; ++j) v[j] = bf2f(raw[j]);
  float mx = v[0];
#pragma unroll
  for (int j = 1; j < 8; ++j) mx = fmaxf(mx, v[j]);
#pragma unroll
  for (int off = 32; off; off >>= 1) mx = fmaxf(mx, __shfl_xor(mx, off, 64));
  if (lane == 0) redm[wid] = mx;
  __syncthreads();
  mx = fmaxf(fmaxf(redm[0], redm[1]), fmaxf(redm[2], redm[3]));
  float s = 0.f;
#pragma unroll
  for (int j = 0; j < 8; ++j) { v[j] = __expf(v[j] - mx); s += v[j]; }
#pragma unroll
  for (int off = 32; off; off >>= 1) s += __shfl_xor(s, off, 64);
  if (lane == 0) reds[wid] = s;
  __syncthreads();
  s = reds[0] + reds[1] + reds[2] + reds[3];
  const float inv = 1.f / s;
  u16x8 o;
#pragma unroll
  for (int j = 0; j < 8; ++j) o[j] = f2bf(v[j] * inv);
  ((u16x8*)row)[t] = o;
}

// ===== shared 256x256 8-phase machinery (QKV persistent GEMM) =============
DEVINL bf16x8 ldfrag(const unsigned short* p, int row, int kx) {
  return *(const bf16x8*)((const char*)p + row * 128 + kx);
}

#define BARSB() do { __builtin_amdgcn_s_barrier(); \
                     __builtin_amdgcn_sched_barrier(0); } while (0)
#define LGK0() asm volatile("s_waitcnt lgkmcnt(0)")
#define VM6()  asm volatile("s_waitcnt vmcnt(6)")

#define MF16(rb, aArr, bArr) do { \
  _Pragma("unroll") for (int m_ = 0; m_ < 4; ++m_) \
  _Pragma("unroll") for (int n_ = 0; n_ < 4; ++n_) \
    acc[(rb) + m_][n_] = __builtin_amdgcn_mfma_f32_16x16x32_bf16( \
        aArr[m_], bArr[n_], acc[(rb) + m_][n_], 0, 0, 0); \
} while (0)

#define STG_A(b, h, gk) do { \
  const char* s_ = srcA + (h) * 262144 + (long)(((gk) & 15)) * 128; \
  gload_lds16((const unsigned short*)(s_ + la0), \
              dA + (b) * 16384 + (h) * 8192 + dO0); \
  gload_lds16((const unsigned short*)(s_ + la1), \
              dA + (b) * 16384 + (h) * 8192 + dO1); } while (0)
#define STG_B(b, h, gk) do { \
  int t_ = (gk) >> 4; if (t_ >= len) t_ = len - 1; \
  const char* s_ = Bbase + ((long)(bnStart + t_) << 19) + \
                   (h) * 262144 + (long)(((gk) & 15)) * 128; \
  gload_lds16((const unsigned short*)(s_ + la0), \
              dB + (b) * 16384 + (h) * 8192 + dO0); \
  gload_lds16((const unsigned short*)(s_ + la1), \
              dB + (b) * 16384 + (h) * 8192 + dO1); } while (0)

#define KTILE(BUF, S1, S2, S3, S4) do { \
  bf16x8 b0_[4], b1_[4], aA_[4], aB_[4], aC_[4], aD_[4]; \
  _Pragma("unroll") for (int n = 0; n < 4; ++n) { \
    b0_[n] = ldfrag(dB + (BUF) * 16384, wn * 64 + n * 16 + lr, kx0); \
    b1_[n] = ldfrag(dB + (BUF) * 16384, wn * 64 + n * 16 + lr, kx1); } \
  _Pragma("unroll") for (int m = 0; m < 4; ++m) \
    aA_[m] = ldfrag(dA + (BUF) * 16384, wm * 128 + m * 16 + lr, kx0); \
  S1; \
  BARSB(); LGK0(); __builtin_amdgcn_s_setprio(1); \
  MF16(0, aA_, b0_); \
  __builtin_amdgcn_s_setprio(0); BARSB(); \
  _Pragma("unroll") for (int m = 0; m < 4; ++m) { \
    aB_[m] = ldfrag(dA + (BUF) * 16384, wm * 128 + (4 + m) * 16 + lr, kx0); \
    aC_[m] = ldfrag(dA + (BUF) * 16384, wm * 128 + (4 + m) * 16 + lr, kx1); } \
  S2; \
  BARSB(); LGK0(); __builtin_amdgcn_s_setprio(1); \
  MF16(4, aB_, b0_); \
  __builtin_amdgcn_s_setprio(0); BARSB(); \
  _Pragma("unroll") for (int m = 0; m < 4; ++m) \
    aD_[m] = ldfrag(dA + (BUF) * 16384, wm * 128 + m * 16 + lr, kx1); \
  S3; \
  BARSB(); LGK0(); __builtin_amdgcn_s_setprio(1); \
  MF16(4, aC_, b1_); \
  __builtin_amdgcn_s_setprio(0); BARSB(); \
  S4; VM6(); \
  BARSB(); LGK0(); __builtin_amdgcn_s_setprio(1); \
  MF16(0, aD_, b1_); \
  __builtin_amdgcn_s_setprio(0); BARSB(); \
} while (0)

#define G256_PRELUDE() \
  const int tid = threadIdx.x, wid = tid >> 6, lane = tid & 63; \
  const int wm = wid >> 2, wn = wid & 3; \
  const int lr = lane & 15; \
  const int kq = (lane >> 4) << 4; \
  const int xr = (lane & 7) << 4; \
  const int kx0 = kq ^ xr; \
  const int kx1 = (64 | kq) ^ xr; \
  const int loff0 = wid * 1024 + lane * 16; \
  const int loff1 = loff0 + 8192; \
  const int r0 = loff0 >> 7, r1 = loff1 >> 7; \
  const int c0 = (loff0 & 127) ^ ((r0 & 7) << 4); \
  const int c1 = (loff1 & 127) ^ ((r1 & 7) << 4); \
  const long la0 = (long)r0 * 2048 + c0; \
  const long la1 = (long)r1 * 2048 + c1; \
  unsigned short* dA = lds; \
  unsigned short* dB = lds + 32768; \
  const int dO0 = wid * 512, dO1 = 4096 + wid * 512

// ---- persistent 256² QKV: [8192][3072] = hb @ [Wq;Wk;Wv]^T + biases ------
__global__ __launch_bounds__(512, 2) void gemm256_qkv(
    const unsigned short* __restrict__ A, const unsigned short* __restrict__ B,
    unsigned short* __restrict__ Qb, unsigned short* __restrict__ Kb,
    unsigned short* __restrict__ Vt,
    const float* __restrict__ bq, const float* __restrict__ bk,
    const float* __restrict__ bv)
{
  __shared__ __align__(16) unsigned short lds[65536];  // 128 KiB
  G256_PRELUDE();

  const int bid = blockIdx.x;
  const int g = bid & 7;
  const int j = bid >> 3;
  const int bm = g * 4 + (j & 3);
  const int q = j >> 2;                        // 0..7
  const int bnStart = (q < 4) ? 2 * q : 8 + (q - 4);
  const int len = (q < 4) ? 2 : 1;             // 4*2 + 4*1 = 12 bn tiles

  const char* srcA = (const char*)A + ((long)bm << 19);
  const char* Bbase = (const char*)B;

  f32x4 acc[8][4] = {};

  STG_B(0, 0, 0); STG_B(0, 1, 0); STG_A(0, 0, 0); STG_A(0, 1, 0);
  STG_B(1, 0, 1); STG_B(1, 1, 1); STG_A(1, 0, 1);
  VM6();
  BARSB();

  for (int t = 0; t < len; ++t) {
#pragma unroll 1
    for (int it = 0; it < 8; ++it) {
      const int gk = t * 16 + 2 * it;
      KTILE(0, STG_A(1, 1, gk + 1), STG_B(0, 0, gk + 2), STG_B(0, 1, gk + 2),
            STG_A(0, 0, gk + 2));
      KTILE(1, STG_A(0, 1, gk + 2), STG_B(1, 0, gk + 3), STG_B(1, 1, gk + 3),
            STG_A(1, 0, gk + 3));
    }
    const int bnT = bnStart + t;
    const int sector = bnT >> 2;               // 0=Q, 1=K, 2=V
    const int colb = (bnT & 3) * 256;
    const float* bias_s = (sector == 0) ? bq : (sector == 1) ? bk : bv;
    const int q4 = (lane >> 4) * 4;
    if (sector < 2) {
      unsigned short* C = (sector == 0) ? Qb : Kb;
#pragma unroll
      for (int n = 0; n < 4; ++n) {
        const int col = colb + wn * 64 + n * 16 + lr;
        const float bb = bias_s[col];
#pragma unroll
        for (int m = 0; m < 8; ++m) {
          const long row = (long)bm * 256 + wm * 128 + m * 16 + q4;
#pragma unroll
          for (int i = 0; i < 4; ++i)
            C[(row + i) * 1024 + col] = f2bf(acc[m][n][i] + bb);
        }
      }
    } else {
#pragma unroll
      for (int n = 0; n < 4; ++n) {
        const int col = colb + wn * 64 + n * 16 + lr;   // d-dim
        const float bb = bias_s[col];
#pragma unroll
        for (int m = 0; m < 8; ++m) {
          const long row = (long)bm * 256 + wm * 128 + m * 16 + q4;  // seq
          const int b = (int)(row >> 11);
          const int srow = (int)(row & 2047);
          ushort4 o;
          o.x = f2bf(acc[m][n][0] + bb);
          o.y = f2bf(acc[m][n][1] + bb);
          o.z = f2bf(acc[m][n][2] + bb);
          o.w = f2bf(acc[m][n][3] + bb);
          *(ushort4*)(Vt + (long)b * (1024L * 2048) + (long)col * 2048 + srow) = o;
        }
      }
    }
    VM6();
#pragma unroll
    for (int m = 0; m < 8; ++m)
#pragma unroll
      for (int n = 0; n < 4; ++n)
        acc[m][n] = f32x4{0.f, 0.f, 0.f, 0.f};
  }
}

// ==== persistent 128x256 FC, BK=32, 3-buffer counted-vmcnt, 2 blocks/CU ===
// C[8192][32000] = A @ Wfc^T + bias (f32, nt stores).
// 512 blocks: XCD g pins bm in {8g..8g+7} (2 MB A in L2); q = j>>3 walks
// the 125-bn split. Depth-2 rolling pipeline: stage kstep+2 (3 gloads) ->
// vmcnt(6) -> barrier -> ds_read frags -> 16 MFMA (setprio) -> barrier.
// LDS 72 KB (3 x [A 8K | B 16K]) -> 2 blocks/CU (launch_bounds(512,4)):
// cross-block TLP hides the latency stalls that cap the 1-block FC at
// MfmaUtil 32%. Bank swizzle: slot' = q ^ ((r ^ (r>>2)) & 3), applied
// inverse on the global source and on the LDS read (rule #21).
__global__ __launch_bounds__(512, 4) void gemm128_fc(
    const unsigned short* __restrict__ A, const unsigned short* __restrict__ B,
    float* __restrict__ C, const float* __restrict__ bias)
{
  constexpr int N = 32000;
  __shared__ __align__(16) char lds[3 * 24576];   // 72 KiB
  const int tid = threadIdx.x, wid = tid >> 6, lane = tid & 63;
  const int wm = wid >> 2, wn = wid & 3;
  const int lr = lane & 15, q = lane >> 4;

  // persistent mapping: XCD g pins 8 bm panels; q8 walks bn split
  const int bid = blockIdx.x;
  const int g = bid & 7;
  const int j = bid >> 3;                 // 0..63
  const int bm = g * 8 + (j & 7);         // 0..63 (x128 rows)
  const int q8 = j >> 3;                  // 0..7
  const int bnStart = (q8 < 5) ? 16 * q8 : 80 + (q8 - 5) * 15;
  const int len = (q8 < 5) ? 16 : 15;
  const int lastK = len * 32 - 1;

  // staging lane offsets (pre-swizzled global source, linear LDS dest)
  const int o = tid * 16;                 // byte offset in 8 KB region
  const int rA = o >> 6, pA = (o >> 4) & 3;
  const int fA = (rA ^ (rA >> 2)) & 3;
  const long sA_off = (long)rA * 2048 + ((pA ^ fA) << 4);
  const int rB1 = rA, rB2 = rA + 128;
  const int fB1 = fA;
  const int fB2 = (rB2 ^ (rB2 >> 2)) & 3;
  const long sB1_off = (long)rB1 * 2048 + ((pA ^ fB1) << 4);
  const long sB2_off = (long)rB2 * 2048 + ((pA ^ fB2) << 4);
  const char* srcA = (const char*)A + ((long)bm << 18);   // 128 rows * 2 KB
  const char* Bbase = (const char*)B;

  // fragment read offsets (swizzled)
  int aoff[4], boff[4];
#pragma unroll
  for (int m = 0; m < 4; ++m) {
    const int r = wm * 64 + m * 16 + lr;
    aoff[m] = r * 64 + ((q ^ ((r ^ (r >> 2)) & 3)) << 4);
  }
#pragma unroll
  for (int n = 0; n < 4; ++n) {
    const int r = wn * 64 + n * 16 + lr;
    boff[n] = r * 64 + ((q ^ ((r ^ (r >> 2)) & 3)) << 4);
  }

  f32x4 acc[4][4] = {};
  float bv[4];
#pragma unroll
  for (int n = 0; n < 4; ++n)
    bv[n] = bias[(long)bnStart * 256 + wn * 64 + n * 16 + lr];

#define STG3_FC(kk, buf) do { \
    const int kc = (kk) <= lastK ? (kk) : lastK; \
    int tt = kc >> 5; \
    const long kb = (long)(kc & 31) * 64; \
    char* db = lds + (buf) * 24576; \
    gload_lds16((const unsigned short*)(srcA + kb + sA_off), \
                (unsigned short*)(db + o)); \
    const char* sB = Bbase + ((long)(bnStart + tt) << 19) + kb; \
    gload_lds16((const unsigned short*)(sB + sB1_off), \
                (unsigned short*)(db + 8192 + o)); \
    gload_lds16((const unsigned short*)(sB + sB2_off), \
                (unsigned short*)(db + 16384 + o)); \
  } while (0)

  // prologue: ksteps 0,1 into buffers 0,1
  STG3_FC(0, 0);
  STG3_FC(1, 1);

  int cur = 0, nxt = 1, pre = 2;
  for (int t = 0; t < len; ++t) {
#pragma unroll 1
    for (int ks = 0; ks < 32; ++ks) {
      const int gk = t * 32 + ks;
      STG3_FC(gk + 2, pre);
      asm volatile("s_waitcnt vmcnt(6)");
      __builtin_amdgcn_s_barrier();
      __builtin_amdgcn_sched_barrier(0);
      const char* pAb = lds + cur * 24576;
      const char* pBb = pAb + 8192;
      bf16x8 af[4], bg[4];
#pragma unroll
      for (int m = 0; m < 4; ++m)
        af[m] = *(const bf16x8*)(pAb + aoff[m]);
#pragma unroll
      for (int n = 0; n < 4; ++n)
        bg[n] = *(const bf16x8*)(pBb + boff[n]);
      __builtin_amdgcn_s_setprio(1);
#pragma unroll
      for (int m = 0; m < 4; ++m)
#pragma unroll
        for (int n = 0; n < 4; ++n)
          acc[m][n] = __builtin_amdgcn_mfma_f32_16x16x32_bf16(af[m], bg[n],
                                                              acc[m][n], 0, 0, 0);
      __builtin_amdgcn_s_setprio(0);
      __builtin_amdgcn_s_barrier();
      __builtin_amdgcn_sched_barrier(0);
      const int tmp = cur; cur = nxt; nxt = pre; pre = tmp;
    }
    // epilogue for tile t: scattered nt stores, drain at boundary
    const long bnRow = ((long)bnStart + t) * 256;
    const int q4 = q * 4;
#pragma unroll
    for (int m = 0; m < 4; ++m) {
      const long row = (long)bm * 128 + wm * 64 + m * 16 + q4;
#pragma unroll
      for (int i = 0; i < 4; ++i) {
        float* orow = C + (row + i) * (long)N;
#pragma unroll
        for (int n = 0; n < 4; ++n)
          __builtin_nontemporal_store(acc[m][n][i] + bv[n],
                                      &orow[bnRow + wn * 64 + n * 16 + lr]);
      }
    }
    asm volatile("s_waitcnt vmcnt(6)");   // drain stores; staged loads landed
    const int tn = (t + 1 < len) ? t + 1 : t;
#pragma unroll
    for (int n = 0; n < 4; ++n)
      bv[n] = bias[((long)bnStart + tn) * 256 + wn * 64 + n * 16 + lr];
#pragma unroll
    for (int m = 0; m < 4; ++m)
#pragma unroll
      for (int n = 0; n < 4; ++n)
        acc[m][n] = f32x4{0.f, 0.f, 0.f, 0.f};
  }
#undef STG3_FC
}

// ---------------------------------------------------------------------------
extern "C" void kernel_launch(void* const* d_in, const int* in_sizes, int n_in,
                              void* d_out, int out_size, void* d_ws, size_t ws_size,
                              hipStream_t stream)
{
  const int*   x   = (const int*)d_in[0];
  const float* tok = (const float*)d_in[1];
  const float* pos = (const float*)d_in[2];
  const float* Wq  = (const float*)d_in[3];
  const float* bq  = (const float*)d_in[4];
  const float* Wk  = (const float*)d_in[5];
  const float* bk  = (const float*)d_in[6];
  const float* Wv  = (const float*)d_in[7];
  const float* bv  = (const float*)d_in[8];
  const float* Wfc = (const float*)d_in[9];
  const float* bfc = (const float*)d_in[10];
  float* out = (float*)d_out;

  char* ws = (char*)d_ws;
  unsigned short* hb   = (unsigned short*)(ws);              // 16 MB  [8192][1024]
  unsigned short* Wqb  = (unsigned short*)(ws + 16777216);   // 6 MB [Wq;Wk;Wv]
  unsigned short* Wfcb = (unsigned short*)(ws + 23068672);   // 62.5 MB [32000][1024]
  unsigned short* Qb   = (unsigned short*)(ws + 88604672);   // 16 MB
  unsigned short* Kb   = (unsigned short*)(ws + 105381888);  // 16 MB
  unsigned short* Vt   = (unsigned short*)(ws + 122159104);  // 16 MB [4][1024][2048]
  unsigned short* Sc   = (unsigned short*)(ws + 138936320);  // 32 MB [4][2048][2048]
  unsigned short* AO   = hb;  // alias: h dead after QKV

  dim3 blk(256);
  // embed + qkv-weight cvt (heterogeneous grid)
  embed_cvtq_kernel<<<dim3(8704), blk, 0, stream>>>(x, tok, pos, hb,
                                                    Wq, Wk, Wv, Wqb);
  // fused Q,K,V — persistent 256² 8-phase
  gemm256_qkv<<<dim3(256), dim3(512), 0, stream>>>(hb, Wqb, Qb, Kb, Vt,
                                                   bq, bk, bv);
  // scores GEMM (blocks 1024..2047) + Wfc cvt (blocks 0..1023) overlapped
  scores_cvt_kernel<<<dim3(2048), blk, 0, stream>>>(Qb, Kb, Sc, Wfc, Wfcb);
  softmax_kernel<<<8192, 256, 0, stream>>>(Sc);
  // AO[b] = P[b] @ Vt[b]^T
  gemm_bt<0><<<dim3(512), blk, 0, stream>>>(Sc, Vt, AO, nullptr, 1.f,
      2048, 1024, 2048, 2048L * 2048, 1024L * 2048, 2048L * 1024, 0, 0, 1);
  // logits = AO @ Wfc^T + bfc  (persistent 128x256, 2 blocks/CU, nt stores)
  gemm128_fc<<<dim3(512), dim3(512), 0, stream>>>(AO, Wfcb, out, bfc);
}

// Round 19
// 748.924 us; speedup vs baseline: 1.1144x; 1.1144x over previous
//
#include <hip/hip_runtime.h>
#include <hip/hip_bf16.h>
#include <stdint.h>

typedef __bf16 bf16x8 __attribute__((ext_vector_type(8)));
typedef float f32x4 __attribute__((ext_vector_type(4)));
typedef unsigned short u16x8 __attribute__((ext_vector_type(8)));

#define DEVINL static __device__ __forceinline__

// f32 -> bf16 round-to-nearest-even (finite values)
DEVINL unsigned short f2bf(float f) {
  unsigned u = __builtin_bit_cast(unsigned, f);
  unsigned r = (u + 0x7FFFu + ((u >> 16) & 1u)) >> 16;
  return (unsigned short)r;
}
DEVINL float bf2f(unsigned short u) {
  return __builtin_bit_cast(float, ((unsigned)u) << 16);
}

DEVINL void gload_lds16(const unsigned short* g, unsigned short* l) {
  __builtin_amdgcn_global_load_lds(
      (const __attribute__((address_space(1))) void*)g,
      (__attribute__((address_space(3))) void*)l, 16, 0, 0);
}

// ---- embed + qkv-weight cvt, one launch (heterogeneous grid) -------------
__global__ __launch_bounds__(256) void embed_cvtq_kernel(
    const int* __restrict__ x, const float* __restrict__ tok,
    const float* __restrict__ pos, unsigned short* __restrict__ hb,
    const float* __restrict__ wq, const float* __restrict__ wk,
    const float* __restrict__ wv, unsigned short* __restrict__ wqkvb)
{
  if (blockIdx.x >= 8192) {
    const int b = blockIdx.x - 8192;  // 0..511
    for (long i = (long)b * 256 + threadIdx.x; i < 786432; i += 512 * 256) {
      const float* src;
      long off;
      if (i < 262144)      { src = wq; off = i; }
      else if (i < 524288) { src = wk; off = i - 262144; }
      else                 { src = wv; off = i - 524288; }
      float4 v = ((const float4*)src)[off];
      ushort4 o;
      o.x = f2bf(v.x); o.y = f2bf(v.y); o.z = f2bf(v.z); o.w = f2bf(v.w);
      ((ushort4*)wqkvb)[i] = o;
    }
    return;
  }
  const int bs = blockIdx.x;           // 0..8191  (b*2048 + s)
  const int s  = bs & 2047;
  const long trow = (long)x[bs] * 1024;
  const int d = threadIdx.x * 4;
  const float4 t = *(const float4*)(tok + trow + d);
  const float4 p = *(const float4*)(pos + (long)s * 1024 + d);
  ushort4 o;
  o.x = f2bf(t.x + p.x);
  o.y = f2bf(t.y + p.y);
  o.z = f2bf(t.z + p.z);
  o.w = f2bf(t.w + p.w);
  *(ushort4*)(hb + (long)bs * 1024 + d) = o;
}

// ---------------- GEMM: C[m,n] = scale * sum_k A[m,k]*B[n,k] + bias[n] ----
// m97-structure 128x128 kernel — used for PV.
template<int OUTMODE>
__global__ __launch_bounds__(256) void gemm_bt(
    const unsigned short* __restrict__ A, const unsigned short* __restrict__ B,
    void* __restrict__ Cout, const float* __restrict__ bias,
    float scale, int M, int N, int K,
    long sA, long sB, long sC, int Mb, long tStride, int mapMode)
{
  __shared__ __align__(16) unsigned short lA[128 * 32];
  __shared__ __align__(16) unsigned short lB[128 * 32];
  const int tid = threadIdx.x, wid = tid >> 6, lane = tid & 63;
  int bx, by, bz;
  if (mapMode == 0) {
    bx = blockIdx.x; by = blockIdx.y; bz = blockIdx.z;
  } else {
    const int bid = blockIdx.x;
    const int g = bid & 7, jj = bid >> 3;
    bz = g >> 1;
    by = (g & 1) * 8 + (jj & 7);
    bx = jj >> 3;
  }
  A += (long)bz * sA;
  B += (long)bz * sB;
  const int bm = by * 128, bn = bx * 128;

  const int c0 = wid * 64 + lane, c1 = c0 + 256;
  const unsigned short* gA0 = A + (long)(bm + (c0 >> 2)) * K + (c0 & 3) * 8;
  const unsigned short* gA1 = A + (long)(bm + (c1 >> 2)) * K + (c1 & 3) * 8;
  const unsigned short* gB0 = B + (long)(bn + (c0 >> 2)) * K + (c0 & 3) * 8;
  const unsigned short* gB1 = B + (long)(bn + (c1 >> 2)) * K + (c1 & 3) * 8;
  unsigned short* lA0 = lA + wid * 512;
  unsigned short* lA1 = lA + 2048 + wid * 512;
  unsigned short* lB0 = lB + wid * 512;
  unsigned short* lB1 = lB + 2048 + wid * 512;

  const int wr = (wid >> 1) * 64, wc = (wid & 1) * 64;
  const int lr = lane & 15, lk = (lane >> 4) * 8;

  f32x4 acc[4][4] = {};
  const int nk = K >> 5;
  for (int kt = 0; kt < nk; ++kt) {
    const int ko = kt << 5;
    gload_lds16(gA0 + ko, lA0);
    gload_lds16(gA1 + ko, lA1);
    gload_lds16(gB0 + ko, lB0);
    gload_lds16(gB1 + ko, lB1);
    __syncthreads();
    bf16x8 af[4], bg[4];
#pragma unroll
    for (int m = 0; m < 4; ++m)
      af[m] = *(const bf16x8*)(const void*)(lA + (wr + m * 16 + lr) * 32 + lk);
#pragma unroll
    for (int n = 0; n < 4; ++n)
      bg[n] = *(const bf16x8*)(const void*)(lB + (wc + n * 16 + lr) * 32 + lk);
#pragma unroll
    for (int m = 0; m < 4; ++m)
#pragma unroll
      for (int n = 0; n < 4; ++n)
        acc[m][n] = __builtin_amdgcn_mfma_f32_16x16x32_bf16(af[m], bg[n],
                                                            acc[m][n], 0, 0, 0);
    __syncthreads();
  }

  const int r0 = bm + wr + ((lane >> 4) << 2);
  const int cbase = bn + wc + lr;
#pragma unroll
  for (int n = 0; n < 4; ++n) {
    const int col = cbase + n * 16;
    const float bv = bias ? bias[col] : 0.f;
#pragma unroll
    for (int m = 0; m < 4; ++m) {
      const int row0 = r0 + m * 16;
      if (OUTMODE == 2) {
        float* C = (float*)Cout + (long)bz * sC;
#pragma unroll
        for (int i = 0; i < 4; ++i)
          C[(long)(row0 + i) * N + col] = acc[m][n][i] * scale + bv;
      } else if (OUTMODE == 0) {
        unsigned short* C = (unsigned short*)Cout + (long)bz * sC;
#pragma unroll
        for (int i = 0; i < 4; ++i)
          C[(long)(row0 + i) * N + col] = f2bf(acc[m][n][i] * scale + bv);
      } else {  // transposed write Vt[b][col][srow]
        unsigned short* C = (unsigned short*)Cout;
        const int b = row0 / Mb;
        const int srow = row0 - b * Mb;
        ushort4 o;
        o.x = f2bf(acc[m][n][0] * scale + bv);
        o.y = f2bf(acc[m][n][1] * scale + bv);
        o.z = f2bf(acc[m][n][2] * scale + bv);
        o.w = f2bf(acc[m][n][3] * scale + bv);
        *(ushort4*)(C + (long)b * tStride + (long)col * Mb + srow) = o;
      }
    }
  }
}

// ---- scores GEMM + Wfc cvt, one launch (heterogeneous grid) --------------
__global__ __launch_bounds__(256) void scores_cvt_kernel(
    const unsigned short* __restrict__ Qb, const unsigned short* __restrict__ Kb,
    unsigned short* __restrict__ Sc,
    const float* __restrict__ wfc, unsigned short* __restrict__ wfcb)
{
  __shared__ __align__(16) unsigned short lA[128 * 32];
  __shared__ __align__(16) unsigned short lB[128 * 32];
  if (blockIdx.x < 1024) {
    for (long i = (long)blockIdx.x * 256 + threadIdx.x; i < 8192000;
         i += 1024 * 256) {
      float4 v = ((const float4*)wfc)[i];
      ushort4 o;
      o.x = f2bf(v.x); o.y = f2bf(v.y); o.z = f2bf(v.z); o.w = f2bf(v.w);
      ((ushort4*)wfcb)[i] = o;
    }
    return;
  }
  constexpr int K = 1024, N = 2048;
  const int tid = threadIdx.x, wid = tid >> 6, lane = tid & 63;
  const int bid = blockIdx.x - 1024;            // 0..1023
  const int g = bid & 7, jj = bid >> 3;
  const int bz = g >> 1;
  const int by = (g & 1) * 8 + (jj & 7);
  const int bx = jj >> 3;
  const unsigned short* A = Qb + (long)bz * (2048L * 1024);
  const unsigned short* B = Kb + (long)bz * (2048L * 1024);
  unsigned short* C = Sc + (long)bz * (2048L * 2048);
  const int bm = by * 128, bn = bx * 128;

  const int c0 = wid * 64 + lane, c1 = c0 + 256;
  const unsigned short* gA0 = A + (long)(bm + (c0 >> 2)) * K + (c0 & 3) * 8;
  const unsigned short* gA1 = A + (long)(bm + (c1 >> 2)) * K + (c1 & 3) * 8;
  const unsigned short* gB0 = B + (long)(bn + (c0 >> 2)) * K + (c0 & 3) * 8;
  const unsigned short* gB1 = B + (long)(bn + (c1 >> 2)) * K + (c1 & 3) * 8;
  unsigned short* lA0 = lA + wid * 512;
  unsigned short* lA1 = lA + 2048 + wid * 512;
  unsigned short* lB0 = lB + wid * 512;
  unsigned short* lB1 = lB + 2048 + wid * 512;

  const int wr = (wid >> 1) * 64, wc = (wid & 1) * 64;
  const int lr = lane & 15, lk = (lane >> 4) * 8;

  f32x4 acc[4][4] = {};
  for (int kt = 0; kt < 32; ++kt) {
    const int ko = kt << 5;
    gload_lds16(gA0 + ko, lA0);
    gload_lds16(gA1 + ko, lA1);
    gload_lds16(gB0 + ko, lB0);
    gload_lds16(gB1 + ko, lB1);
    __syncthreads();
    bf16x8 af[4], bg[4];
#pragma unroll
    for (int m = 0; m < 4; ++m)
      af[m] = *(const bf16x8*)(const void*)(lA + (wr + m * 16 + lr) * 32 + lk);
#pragma unroll
    for (int n = 0; n < 4; ++n)
      bg[n] = *(const bf16x8*)(const void*)(lB + (wc + n * 16 + lr) * 32 + lk);
#pragma unroll
    for (int m = 0; m < 4; ++m)
#pragma unroll
      for (int n = 0; n < 4; ++n)
        acc[m][n] = __builtin_amdgcn_mfma_f32_16x16x32_bf16(af[m], bg[n],
                                                            acc[m][n], 0, 0, 0);
    __syncthreads();
  }

  const int r0 = bm + wr + ((lane >> 4) << 2);
  const int cbase = bn + wc + lr;
#pragma unroll
  for (int n = 0; n < 4; ++n) {
    const int col = cbase + n * 16;
#pragma unroll
    for (int m = 0; m < 4; ++m) {
      const int row0 = r0 + m * 16;
#pragma unroll
      for (int i = 0; i < 4; ++i)
        C[(long)(row0 + i) * N + col] = f2bf(acc[m][n][i] * 0.03125f);
    }
  }
}

// ---------------- row softmax in place over 2048 bf16 ---------------------
__global__ __launch_bounds__(256) void softmax_kernel(unsigned short* __restrict__ S)
{
  unsigned short* row = S + (long)blockIdx.x * 2048;
  const int t = threadIdx.x, lane = t & 63, wid = t >> 6;
  __shared__ float redm[4], reds[4];
  u16x8 raw = ((const u16x8*)row)[t];
  float v[8];
#pragma unroll
  for (int j = 0; j < 8; ++j) v[j] = bf2f(raw[j]);
  float mx = v[0];
#pragma unroll
  for (int j = 1; j < 8; ++j) mx = fmaxf(mx, v[j]);
#pragma unroll
  for (int off = 32; off; off >>= 1) mx = fmaxf(mx, __shfl_xor(mx, off, 64));
  if (lane == 0) redm[wid] = mx;
  __syncthreads();
  mx = fmaxf(fmaxf(redm[0], redm[1]), fmaxf(redm[2], redm[3]));
  float s = 0.f;
#pragma unroll
  for (int j = 0; j < 8; ++j) { v[j] = __expf(v[j] - mx); s += v[j]; }
#pragma unroll
  for (int off = 32; off; off >>= 1) s += __shfl_xor(s, off, 64);
  if (lane == 0) reds[wid] = s;
  __syncthreads();
  s = reds[0] + reds[1] + reds[2] + reds[3];
  const float inv = 1.f / s;
  u16x8 o;
#pragma unroll
  for (int j = 0; j < 8; ++j) o[j] = f2bf(v[j] * inv);
  ((u16x8*)row)[t] = o;
}

// ===== shared 256x256 8-phase machinery (FC + QKV persistent GEMMs) =======
DEVINL bf16x8 ldfrag(const unsigned short* p, int row, int kx) {
  return *(const bf16x8*)((const char*)p + row * 128 + kx);
}

#define BARSB() do { __builtin_amdgcn_s_barrier(); \
                     __builtin_amdgcn_sched_barrier(0); } while (0)
#define LGK0() asm volatile("s_waitcnt lgkmcnt(0)")
#define VM6()  asm volatile("s_waitcnt vmcnt(6)")

#define MF16(rb, aArr, bArr) do { \
  _Pragma("unroll") for (int m_ = 0; m_ < 4; ++m_) \
  _Pragma("unroll") for (int n_ = 0; n_ < 4; ++n_) \
    acc[(rb) + m_][n_] = __builtin_amdgcn_mfma_f32_16x16x32_bf16( \
        aArr[m_], bArr[n_], acc[(rb) + m_][n_], 0, 0, 0); \
} while (0)

#define STG_A(b, h, gk) do { \
  const char* s_ = srcA + (h) * 262144 + (long)(((gk) & 15)) * 128; \
  gload_lds16((const unsigned short*)(s_ + la0), \
              dA + (b) * 16384 + (h) * 8192 + dO0); \
  gload_lds16((const unsigned short*)(s_ + la1), \
              dA + (b) * 16384 + (h) * 8192 + dO1); } while (0)
#define STG_B(b, h, gk) do { \
  int t_ = (gk) >> 4; if (t_ >= len) t_ = len - 1; \
  const char* s_ = Bbase + ((long)(bnStart + t_) << 19) + \
                   (h) * 262144 + (long)(((gk) & 15)) * 128; \
  gload_lds16((const unsigned short*)(s_ + la0), \
              dB + (b) * 16384 + (h) * 8192 + dO0); \
  gload_lds16((const unsigned short*)(s_ + la1), \
              dB + (b) * 16384 + (h) * 8192 + dO1); } while (0)

#define KTILE(BUF, S1, S2, S3, S4) do { \
  bf16x8 b0_[4], b1_[4], aA_[4], aB_[4], aC_[4], aD_[4]; \
  _Pragma("unroll") for (int n = 0; n < 4; ++n) { \
    b0_[n] = ldfrag(dB + (BUF) * 16384, wn * 64 + n * 16 + lr, kx0); \
    b1_[n] = ldfrag(dB + (BUF) * 16384, wn * 64 + n * 16 + lr, kx1); } \
  _Pragma("unroll") for (int m = 0; m < 4; ++m) \
    aA_[m] = ldfrag(dA + (BUF) * 16384, wm * 128 + m * 16 + lr, kx0); \
  S1; \
  BARSB(); LGK0(); __builtin_amdgcn_s_setprio(1); \
  MF16(0, aA_, b0_); \
  __builtin_amdgcn_s_setprio(0); BARSB(); \
  _Pragma("unroll") for (int m = 0; m < 4; ++m) { \
    aB_[m] = ldfrag(dA + (BUF) * 16384, wm * 128 + (4 + m) * 16 + lr, kx0); \
    aC_[m] = ldfrag(dA + (BUF) * 16384, wm * 128 + (4 + m) * 16 + lr, kx1); } \
  S2; \
  BARSB(); LGK0(); __builtin_amdgcn_s_setprio(1); \
  MF16(4, aB_, b0_); \
  __builtin_amdgcn_s_setprio(0); BARSB(); \
  _Pragma("unroll") for (int m = 0; m < 4; ++m) \
    aD_[m] = ldfrag(dA + (BUF) * 16384, wm * 128 + m * 16 + lr, kx1); \
  S3; \
  BARSB(); LGK0(); __builtin_amdgcn_s_setprio(1); \
  MF16(4, aC_, b1_); \
  __builtin_amdgcn_s_setprio(0); BARSB(); \
  S4; VM6(); \
  BARSB(); LGK0(); __builtin_amdgcn_s_setprio(1); \
  MF16(0, aD_, b1_); \
  __builtin_amdgcn_s_setprio(0); BARSB(); \
} while (0)

#define G256_PRELUDE() \
  const int tid = threadIdx.x, wid = tid >> 6, lane = tid & 63; \
  const int wm = wid >> 2, wn = wid & 3; \
  const int lr = lane & 15; \
  const int kq = (lane >> 4) << 4; \
  const int xr = (lane & 7) << 4; \
  const int kx0 = kq ^ xr; \
  const int kx1 = (64 | kq) ^ xr; \
  const int loff0 = wid * 1024 + lane * 16; \
  const int loff1 = loff0 + 8192; \
  const int r0 = loff0 >> 7, r1 = loff1 >> 7; \
  const int c0 = (loff0 & 127) ^ ((r0 & 7) << 4); \
  const int c1 = (loff1 & 127) ^ ((r1 & 7) << 4); \
  const long la0 = (long)r0 * 2048 + c0; \
  const long la1 = (long)r1 * 2048 + c1; \
  unsigned short* dA = lds; \
  unsigned short* dB = lds + 32768; \
  const int dO0 = wid * 512, dO1 = 4096 + wid * 512

// ---- persistent 256² FC: C[8192][32000] = AO @ Wfc^T + bias (f32, nt) ----
__global__ __launch_bounds__(512, 2) void gemm256_fc(
    const unsigned short* __restrict__ A, const unsigned short* __restrict__ B,
    float* __restrict__ C, const float* __restrict__ bias)
{
  constexpr int N = 32000;
  __shared__ __align__(16) unsigned short lds[65536];  // 128 KiB
  G256_PRELUDE();

  // L2-resident-A persistent mapping (R11)
  const int bid = blockIdx.x;
  const int g = bid & 7;
  const int j = bid >> 3;
  const int bm = g * 4 + (j & 3);
  const int q = j >> 2;
  const int bnStart = (q < 5) ? 16 * q : 80 + (q - 5) * 15;
  const int len = (q < 5) ? 16 : 15;

  const char* srcA = (const char*)A + ((long)bm << 19);
  const char* Bbase = (const char*)B;

  f32x4 acc[8][4] = {};
  float bv[4];
#pragma unroll
  for (int n = 0; n < 4; ++n)
    bv[n] = bias[(long)bnStart * 256 + wn * 64 + n * 16 + lr];

  STG_B(0, 0, 0); STG_B(0, 1, 0); STG_A(0, 0, 0); STG_A(0, 1, 0);
  STG_B(1, 0, 1); STG_B(1, 1, 1); STG_A(1, 0, 1);
  VM6();
  BARSB();

  for (int t = 0; t < len; ++t) {
#pragma unroll 1
    for (int it = 0; it < 8; ++it) {
      const int gk = t * 16 + 2 * it;
      KTILE(0, STG_A(1, 1, gk + 1), STG_B(0, 0, gk + 2), STG_B(0, 1, gk + 2),
            STG_A(0, 0, gk + 2));
      KTILE(1, STG_A(0, 1, gk + 2), STG_B(1, 0, gk + 3), STG_B(1, 1, gk + 3),
            STG_A(1, 0, gk + 3));
    }
    const long bnRow = ((long)bnStart + t) * 256;
    const int q4 = (lane >> 4) * 4;
#pragma unroll
    for (int m = 0; m < 8; ++m) {
      const long row = (long)bm * 256 + wm * 128 + m * 16 + q4;
#pragma unroll
      for (int i = 0; i < 4; ++i) {
        float* orow = C + (row + i) * (long)N;
#pragma unroll
        for (int n = 0; n < 4; ++n)
          __builtin_nontemporal_store(acc[m][n][i] + bv[n],
                                      &orow[bnRow + wn * 64 + n * 16 + lr]);
      }
    }
    VM6();
    const int tn = (t + 1 < len) ? t + 1 : t;
#pragma unroll
    for (int n = 0; n < 4; ++n)
      bv[n] = bias[((long)bnStart + tn) * 256 + wn * 64 + n * 16 + lr];
#pragma unroll
    for (int m = 0; m < 8; ++m)
#pragma unroll
      for (int n = 0; n < 4; ++n)
        acc[m][n] = f32x4{0.f, 0.f, 0.f, 0.f};
  }
}

// ---- persistent 256² QKV: [8192][3072] = hb @ [Wq;Wk;Wv]^T + biases ------
__global__ __launch_bounds__(512, 2) void gemm256_qkv(
    const unsigned short* __restrict__ A, const unsigned short* __restrict__ B,
    unsigned short* __restrict__ Qb, unsigned short* __restrict__ Kb,
    unsigned short* __restrict__ Vt,
    const float* __restrict__ bq, const float* __restrict__ bk,
    const float* __restrict__ bv)
{
  __shared__ __align__(16) unsigned short lds[65536];  // 128 KiB
  G256_PRELUDE();

  const int bid = blockIdx.x;
  const int g = bid & 7;
  const int j = bid >> 3;
  const int bm = g * 4 + (j & 3);
  const int q = j >> 2;                        // 0..7
  const int bnStart = (q < 4) ? 2 * q : 8 + (q - 4);
  const int len = (q < 4) ? 2 : 1;             // 4*2 + 4*1 = 12 bn tiles

  const char* srcA = (const char*)A + ((long)bm << 19);
  const char* Bbase = (const char*)B;

  f32x4 acc[8][4] = {};

  STG_B(0, 0, 0); STG_B(0, 1, 0); STG_A(0, 0, 0); STG_A(0, 1, 0);
  STG_B(1, 0, 1); STG_B(1, 1, 1); STG_A(1, 0, 1);
  VM6();
  BARSB();

  for (int t = 0; t < len; ++t) {
#pragma unroll 1
    for (int it = 0; it < 8; ++it) {
      const int gk = t * 16 + 2 * it;
      KTILE(0, STG_A(1, 1, gk + 1), STG_B(0, 0, gk + 2), STG_B(0, 1, gk + 2),
            STG_A(0, 0, gk + 2));
      KTILE(1, STG_A(0, 1, gk + 2), STG_B(1, 0, gk + 3), STG_B(1, 1, gk + 3),
            STG_A(1, 0, gk + 3));
    }
    const int bnT = bnStart + t;
    const int sector = bnT >> 2;               // 0=Q, 1=K, 2=V
    const int colb = (bnT & 3) * 256;
    const float* bias_s = (sector == 0) ? bq : (sector == 1) ? bk : bv;
    const int q4 = (lane >> 4) * 4;
    if (sector < 2) {
      unsigned short* C = (sector == 0) ? Qb : Kb;
#pragma unroll
      for (int n = 0; n < 4; ++n) {
        const int col = colb + wn * 64 + n * 16 + lr;
        const float bb = bias_s[col];
#pragma unroll
        for (int m = 0; m < 8; ++m) {
          const long row = (long)bm * 256 + wm * 128 + m * 16 + q4;
#pragma unroll
          for (int i = 0; i < 4; ++i)
            C[(row + i) * 1024 + col] = f2bf(acc[m][n][i] + bb);
        }
      }
    } else {
#pragma unroll
      for (int n = 0; n < 4; ++n) {
        const int col = colb + wn * 64 + n * 16 + lr;   // d-dim
        const float bb = bias_s[col];
#pragma unroll
        for (int m = 0; m < 8; ++m) {
          const long row = (long)bm * 256 + wm * 128 + m * 16 + q4;  // seq
          const int b = (int)(row >> 11);
          const int srow = (int)(row & 2047);
          ushort4 o;
          o.x = f2bf(acc[m][n][0] + bb);
          o.y = f2bf(acc[m][n][1] + bb);
          o.z = f2bf(acc[m][n][2] + bb);
          o.w = f2bf(acc[m][n][3] + bb);
          *(ushort4*)(Vt + (long)b * (1024L * 2048) + (long)col * 2048 + srow) = o;
        }
      }
    }
    VM6();
#pragma unroll
    for (int m = 0; m < 8; ++m)
#pragma unroll
      for (int n = 0; n < 4; ++n)
        acc[m][n] = f32x4{0.f, 0.f, 0.f, 0.f};
  }
}

// ---------------------------------------------------------------------------
extern "C" void kernel_launch(void* const* d_in, const int* in_sizes, int n_in,
                              void* d_out, int out_size, void* d_ws, size_t ws_size,
                              hipStream_t stream)
{
  const int*   x   = (const int*)d_in[0];
  const float* tok = (const float*)d_in[1];
  const float* pos = (const float*)d_in[2];
  const float* Wq  = (const float*)d_in[3];
  const float* bq  = (const float*)d_in[4];
  const float* Wk  = (const float*)d_in[5];
  const float* bk  = (const float*)d_in[6];
  const float* Wv  = (const float*)d_in[7];
  const float* bv  = (const float*)d_in[8];
  const float* Wfc = (const float*)d_in[9];
  const float* bfc = (const float*)d_in[10];
  float* out = (float*)d_out;

  char* ws = (char*)d_ws;
  unsigned short* hb   = (unsigned short*)(ws);              // 16 MB  [8192][1024]
  unsigned short* Wqb  = (unsigned short*)(ws + 16777216);   // 6 MB [Wq;Wk;Wv]
  unsigned short* Wfcb = (unsigned short*)(ws + 23068672);   // 62.5 MB [32000][1024]
  unsigned short* Qb   = (unsigned short*)(ws + 88604672);   // 16 MB
  unsigned short* Kb   = (unsigned short*)(ws + 105381888);  // 16 MB
  unsigned short* Vt   = (unsigned short*)(ws + 122159104);  // 16 MB [4][1024][2048]
  unsigned short* Sc   = (unsigned short*)(ws + 138936320);  // 32 MB [4][2048][2048]
  unsigned short* AO   = hb;  // alias: h dead after QKV

  dim3 blk(256);
  // embed + qkv-weight cvt (heterogeneous grid)
  embed_cvtq_kernel<<<dim3(8704), blk, 0, stream>>>(x, tok, pos, hb,
                                                    Wq, Wk, Wv, Wqb);
  // fused Q,K,V — persistent 256² 8-phase
  gemm256_qkv<<<dim3(256), dim3(512), 0, stream>>>(hb, Wqb, Qb, Kb, Vt,
                                                   bq, bk, bv);
  // scores GEMM (blocks 1024..2047) + Wfc cvt (blocks 0..1023) overlapped
  scores_cvt_kernel<<<dim3(2048), blk, 0, stream>>>(Qb, Kb, Sc, Wfc, Wfcb);
  softmax_kernel<<<8192, 256, 0, stream>>>(Sc);
  // AO[b] = P[b] @ Vt[b]^T
  gemm_bt<0><<<dim3(512), blk, 0, stream>>>(Sc, Vt, AO, nullptr, 1.f,
      2048, 1024, 2048, 2048L * 2048, 1024L * 2048, 2048L * 1024, 0, 0, 1);
  // logits = AO @ Wfc^T + bfc  (persistent 256², L2-resident-A, nt C-stores)
  gemm256_fc<<<dim3(256), dim3(512), 0, stream>>>(AO, Wfcb, out, bfc);
}